// Round 9
// baseline (356.640 us; speedup 1.0000x reference)
//
#include <hip/hip_runtime.h>

#define B_N   262144
#define PMIN_F 0.001f
#define LOG2E 1.44269504088896340736f
#define LN2   0.69314718055994530942f

typedef _Float16 half4v __attribute__((ext_vector_type(4)));
typedef _Float16 half8  __attribute__((ext_vector_type(8)));
typedef float    floatx4 __attribute__((ext_vector_type(4)));

__device__ __forceinline__ float fexp2(float x) { return __builtin_amdgcn_exp2f(x); }
__device__ __forceinline__ float flog2(float x) { return __builtin_amdgcn_logf(x); }
__device__ __forceinline__ float frcp (float x) { return __builtin_amdgcn_rcpf(x); }

// ---------------------------------------------------------------------------
// Prep: weights fp32 -> f16 in MFMA B-fragment order (unchanged).
//   r in [0,8)   : mm1 W1 16x128, K padded to 32; k==16 row carries b1
//   r in [8,40)  : mm2 Wh 128x128
//   r in [40,104): mm3 Wo 128x248 column-remapped to 256 (31->32 pad per d)
// ---------------------------------------------------------------------------
__global__ __launch_bounds__(64) void prep_kernel(
    const float* __restrict__ W1s, const float* __restrict__ b1s,
    const float* __restrict__ Whs, const float* __restrict__ Wos,
    _Float16* __restrict__ ws)
{
    const int bid   = blockIdx.x;          // 0..415
    const int layer = bid / 104;
    const int r     = bid % 104;
    const int lane  = threadIdx.x;
    const int kg    = lane >> 4;
    const int c     = lane & 15;

    half8 v;
    if (r < 8) {
        const int nt = r, n = nt * 16 + c;
        const float* W1 = W1s + layer * 16 * 128;
        const float* b1 = b1s + layer * 128;
        #pragma unroll
        for (int j = 0; j < 8; ++j) {
            const int k = kg * 8 + j;
            v[j] = (k < 16) ? (_Float16)W1[k * 128 + n]
                 : (k == 16) ? (_Float16)b1[n] : (_Float16)0.f;
        }
    } else if (r < 40) {
        const int f = r - 8, nt = f >> 2, ks = f & 3, n = nt * 16 + c;
        const float* Wh = Whs + layer * 128 * 128;
        #pragma unroll
        for (int j = 0; j < 8; ++j) {
            const int k = ks * 32 + kg * 8 + j;
            v[j] = (_Float16)Wh[k * 128 + n];
        }
    } else {
        const int f = r - 40, nt = f >> 2, ks = f & 3, n = nt * 16 + c;
        const int dd = n >> 5, cc = n & 31;
        const float* Wo = Wos + layer * 128 * 248;
        #pragma unroll
        for (int j = 0; j < 8; ++j) {
            const int k = ks * 32 + kg * 8 + j;
            v[j] = (cc < 31) ? (_Float16)Wo[k * 248 + dd * 31 + cc] : (_Float16)0.f;
        }
    }
    *(half8*)(ws + (size_t)bid * 512 + lane * 8) = v;
}

// ---------------------------------------------------------------------------
// Main: one wave = 32 rows (2 tiles). MFMA sections in nt-groups of 4 ->
// peak accumulator = 32 AGPRs.
// Register model (validated R2/R5/R6/R7/R8): __launch_bounds__(64, N) sets
// TOTAL budget (arch VGPR + AGPR) = 512/N; occupancy = 512/(arch+AGPR).
// N=4 -> 128 total = 96 arch + 32 AGPR; kernel needs ~76 arch -> fits.
// (R2/R6 spilled at N=4 only because AGPR peak was then 64 -> 64 arch.)
// LDS/WG = 2KB xls + 8.25KB R = 10.25KB -> 15 WGs/CU (not binding at 4/SIMD).
// ---------------------------------------------------------------------------
__global__ __launch_bounds__(64, 4) void flow_mfma(
    const float* __restrict__ x_in,
    const float* __restrict__ c_in,
    const float* __restrict__ bhs,
    const float* __restrict__ bos,
    const int*   __restrict__ perms,
    const _Float16* __restrict__ wsW,
    float* __restrict__ out)
{
    __shared__ __align__(16) float    xls[2][256];   // [tile][16 rows][16]
    __shared__ __align__(16) _Float16 R[2][2112];    // h1 / h2 / theta-half, stride 132

    const int lane = threadIdx.x;
    const int q    = lane >> 4;
    const int m    = lane & 15;
    const long long row0 = (long long)blockIdx.x * 32;

    {
        const float4* xp = (const float4*)(x_in + row0 * 16);
        *(float4*)&xls[0][lane * 4] = xp[lane];
        *(float4*)&xls[1][lane * 4] = xp[lane + 64];
    }

    // layer-invariant part of the mm1 A-fragment (c data / bias-one).
    // q==1 lanes read row m's 8 c-floats straight from global (coalesced).
    half8 a1c[2];
    #pragma unroll
    for (int t2 = 0; t2 < 2; ++t2) {
        #pragma unroll
        for (int j = 0; j < 8; ++j) a1c[t2][j] = (_Float16)0.f;
        if (q == 1) {
            const float4* cp = (const float4*)(c_in + (row0 + t2 * 16 + m) * 8);
            const float4 c0 = cp[0], c1 = cp[1];
            a1c[t2][0] = (_Float16)c0.x; a1c[t2][1] = (_Float16)c0.y;
            a1c[t2][2] = (_Float16)c0.z; a1c[t2][3] = (_Float16)c0.w;
            a1c[t2][4] = (_Float16)c1.x; a1c[t2][5] = (_Float16)c1.y;
            a1c[t2][6] = (_Float16)c1.z; a1c[t2][7] = (_Float16)c1.w;
        } else if (q == 2) {
            a1c[t2][0] = (_Float16)1.f;   // k=16 -> bias row
        }
    }
    __syncthreads();

    float ljrow[2] = {0.f, 0.f};

    for (int l = 0; l < 4; ++l) {
        const _Float16* wsl = wsW + (size_t)l * 104 * 512;
        const float* bh = bhs + l * 128;
        const float* bo = bos + l * 248;

        // ================= mm1: [x1,c,1] @ [W1;b1] -> h1 =================
        half8 a1[2];
        #pragma unroll
        for (int t2 = 0; t2 < 2; ++t2) {
            a1[t2] = a1c[t2];
            if (q == 0) {
                const float4 lo = *(const float4*)&xls[t2][m * 16];
                const float4 hi = *(const float4*)&xls[t2][m * 16 + 4];
                a1[t2][0] = (_Float16)lo.x; a1[t2][1] = (_Float16)lo.y;
                a1[t2][2] = (_Float16)lo.z; a1[t2][3] = (_Float16)lo.w;
                a1[t2][4] = (_Float16)hi.x; a1[t2][5] = (_Float16)hi.y;
                a1[t2][6] = (_Float16)hi.z; a1[t2][7] = (_Float16)hi.w;
            }
        }
        #pragma unroll
        for (int g = 0; g < 2; ++g) {
            const floatx4 z = {0.f, 0.f, 0.f, 0.f};
            floatx4 acc0[4], acc1[4];
            #pragma unroll
            for (int nt = 0; nt < 4; ++nt) {
                const half8 b = *(const half8*)(wsl + (g * 4 + nt) * 512 + lane * 8);
                acc0[nt] = __builtin_amdgcn_mfma_f32_16x16x32_f16(a1[0], b, z, 0, 0, 0);
                acc1[nt] = __builtin_amdgcn_mfma_f32_16x16x32_f16(a1[1], b, z, 0, 0, 0);
            }
            #pragma unroll
            for (int nt = 0; nt < 4; ++nt)
                #pragma unroll
                for (int reg = 0; reg < 4; ++reg) {
                    R[0][(q * 4 + reg) * 132 + (g * 4 + nt) * 16 + m] = (_Float16)fmaxf(acc0[nt][reg], 0.f);
                    R[1][(q * 4 + reg) * 132 + (g * 4 + nt) * 16 + m] = (_Float16)fmaxf(acc1[nt][reg], 0.f);
                }
        }
        __syncthreads();

        // ===== mm2: pull h1 A-frags to regs, then overwrite region with h2 =====
        half8 a2[2][4];
        #pragma unroll
        for (int t2 = 0; t2 < 2; ++t2)
            #pragma unroll
            for (int ks = 0; ks < 4; ++ks) {
                const half4v lo = *(const half4v*)&R[t2][m * 132 + ks * 32 + q * 8];
                const half4v hi = *(const half4v*)&R[t2][m * 132 + ks * 32 + q * 8 + 4];
                a2[t2][ks] = __builtin_shufflevector(lo, hi, 0, 1, 2, 3, 4, 5, 6, 7);
            }
        __syncthreads();
        #pragma unroll
        for (int g = 0; g < 2; ++g) {
            floatx4 acc0[4], acc1[4];
            #pragma unroll
            for (int nt = 0; nt < 4; ++nt) {
                const float bb = bh[(g * 4 + nt) * 16 + m];
                acc0[nt][0] = bb; acc0[nt][1] = bb; acc0[nt][2] = bb; acc0[nt][3] = bb;
                acc1[nt] = acc0[nt];
            }
            #pragma unroll
            for (int ks = 0; ks < 4; ++ks)
                #pragma unroll
                for (int nt = 0; nt < 4; ++nt) {
                    const half8 b = *(const half8*)(wsl + (8 + (g * 4 + nt) * 4 + ks) * 512 + lane * 8);
                    acc0[nt] = __builtin_amdgcn_mfma_f32_16x16x32_f16(a2[0][ks], b, acc0[nt], 0, 0, 0);
                    acc1[nt] = __builtin_amdgcn_mfma_f32_16x16x32_f16(a2[1][ks], b, acc1[nt], 0, 0, 0);
                }
            #pragma unroll
            for (int nt = 0; nt < 4; ++nt)
                #pragma unroll
                for (int reg = 0; reg < 4; ++reg) {
                    R[0][(q * 4 + reg) * 132 + (g * 4 + nt) * 16 + m] = (_Float16)fmaxf(acc0[nt][reg], 0.f);
                    R[1][(q * 4 + reg) * 132 + (g * 4 + nt) * 16 + m] = (_Float16)fmaxf(acc1[nt][reg], 0.f);
                }
        }
        __syncthreads();

        // ===== mm3: pull h2 A-frags to regs; theta halves overwrite region =====
        half8 a3[2][4];
        #pragma unroll
        for (int t2 = 0; t2 < 2; ++t2)
            #pragma unroll
            for (int ks = 0; ks < 4; ++ks) {
                const half4v lo = *(const half4v*)&R[t2][m * 132 + ks * 32 + q * 8];
                const half4v hi = *(const half4v*)&R[t2][m * 132 + ks * 32 + q * 8 + 4];
                a3[t2][ks] = __builtin_shufflevector(lo, hi, 0, 1, 2, 3, 4, 5, 6, 7);
            }
        __syncthreads();

        #pragma unroll
        for (int hf = 0; hf < 2; ++hf) {
            // ---- mm3 half: cols [hf*128, hf*128+128) = d in [hf*4, hf*4+4)
            #pragma unroll
            for (int g = 0; g < 2; ++g) {
                floatx4 acc0[4], acc1[4];
                #pragma unroll
                for (int nt4 = 0; nt4 < 4; ++nt4) {
                    const int nt = hf * 8 + g * 4 + nt4;
                    const float bb = ((nt & 1) && m == 15) ? 0.f
                                   : bo[(nt >> 1) * 31 + (nt & 1) * 16 + m];
                    acc0[nt4][0] = bb; acc0[nt4][1] = bb; acc0[nt4][2] = bb; acc0[nt4][3] = bb;
                    acc1[nt4] = acc0[nt4];
                }
                #pragma unroll
                for (int ks = 0; ks < 4; ++ks)
                    #pragma unroll
                    for (int nt4 = 0; nt4 < 4; ++nt4) {
                        const int nt = hf * 8 + g * 4 + nt4;
                        const half8 b = *(const half8*)(wsl + (40 + nt * 4 + ks) * 512 + lane * 8);
                        acc0[nt4] = __builtin_amdgcn_mfma_f32_16x16x32_f16(a3[0][ks], b, acc0[nt4], 0, 0, 0);
                        acc1[nt4] = __builtin_amdgcn_mfma_f32_16x16x32_f16(a3[1][ks], b, acc1[nt4], 0, 0, 0);
                    }
                #pragma unroll
                for (int nt4 = 0; nt4 < 4; ++nt4)
                    #pragma unroll
                    for (int reg = 0; reg < 4; ++reg) {
                        R[0][(q * 4 + reg) * 132 + (g * 4 + nt4) * 16 + m] = (_Float16)acc0[nt4][reg];
                        R[1][(q * 4 + reg) * 132 + (g * 4 + nt4) * 16 + m] = (_Float16)acc1[nt4][reg];
                    }
            }
            __syncthreads();

            // ---- spline half-pass: 128 items (2 tiles x 16 rows x 4 d)
            #pragma unroll
            for (int itp = 0; itp < 2; ++itp) {
                const int t2   = itp;
                const int row  = lane >> 2;
                const int dloc = lane & 3;
                const int d    = hf * 4 + dloc;
                const int base = row * 132 + dloc * 32;

                const half4v v0 = *(const half4v*)&R[t2][base];
                const half4v v1 = *(const half4v*)&R[t2][base + 4];
                const half4v v2 = *(const half4v*)&R[t2][base + 8];
                const half4v v3 = *(const half4v*)&R[t2][base + 12];
                const half4v v4 = *(const half4v*)&R[t2][base + 16];
                const float x2 = xls[t2][row * 16 + 8 + d];

                float tw[10];
                tw[0]=(float)v0[0]; tw[1]=(float)v0[1]; tw[2]=(float)v0[2]; tw[3]=(float)v0[3];
                tw[4]=(float)v1[0]; tw[5]=(float)v1[1]; tw[6]=(float)v1[2]; tw[7]=(float)v1[3];
                tw[8]=(float)v2[0]; tw[9]=(float)v2[1];

                float cx[11], cy[11];
                {
                    float m1 = tw[0];
                    #pragma unroll
                    for (int i = 1; i < 10; ++i) m1 = fmaxf(m1, tw[i]);
                    float se = 0.f;
                    #pragma unroll
                    for (int i = 0; i < 10; ++i) { tw[i] = fexp2((tw[i] - m1) * LOG2E); se += tw[i]; }
                    const float inv198 = 1.98f * frcp(se);   // 2*(1-PMIN*K)*inv
                    cx[0] = -1.f;
                    #pragma unroll
                    for (int i = 0; i < 10; ++i) cx[i + 1] = cx[i] + fmaf(tw[i], inv198, 0.002f);
                }
                {
                    float t0=(float)v2[2], t1=(float)v2[3];
                    float t2v=(float)v3[0], t3=(float)v3[1], t4=(float)v3[2], t5=(float)v3[3];
                    float t6=(float)v4[0], t7=(float)v4[1], t8=(float)v4[2], t9=(float)v4[3];
                    float hm = fmaxf(fmaxf(fmaxf(t0,t1),fmaxf(t2v,t3)),
                                     fmaxf(fmaxf(t4,t5),fmaxf(fmaxf(t6,t7),fmaxf(t8,t9))));
                    float e0=fexp2((t0-hm)*LOG2E), e1=fexp2((t1-hm)*LOG2E);
                    float e2=fexp2((t2v-hm)*LOG2E), e3=fexp2((t3-hm)*LOG2E);
                    float e4=fexp2((t4-hm)*LOG2E), e5=fexp2((t5-hm)*LOG2E);
                    float e6=fexp2((t6-hm)*LOG2E), e7=fexp2((t7-hm)*LOG2E);
                    float e8=fexp2((t8-hm)*LOG2E), e9=fexp2((t9-hm)*LOG2E);
                    const float se = ((e0+e1)+(e2+e3))+((e4+e5)+((e6+e7)+(e8+e9)));
                    const float inv198 = 1.98f * frcp(se);
                    cy[0] = -1.f;
                    cy[1] = cy[0] + fmaf(e0, inv198, 0.002f);
                    cy[2] = cy[1] + fmaf(e1, inv198, 0.002f);
                    cy[3] = cy[2] + fmaf(e2, inv198, 0.002f);
                    cy[4] = cy[3] + fmaf(e3, inv198, 0.002f);
                    cy[5] = cy[4] + fmaf(e4, inv198, 0.002f);
                    cy[6] = cy[5] + fmaf(e5, inv198, 0.002f);
                    cy[7] = cy[6] + fmaf(e6, inv198, 0.002f);
                    cy[8] = cy[7] + fmaf(e7, inv198, 0.002f);
                    cy[9] = cy[8] + fmaf(e8, inv198, 0.002f);
                    cy[10]= cy[9] + fmaf(e9, inv198, 0.002f);
                }

                int cnt = 0;
                #pragma unroll
                for (int i = 0; i < 11; ++i) cnt += (cx[i] < x2) ? 1 : 0;
                const int bidx = cnt - 1;
                const bool inb = (bidx >= 0) && (bidx < 10);
                const int ci = bidx < 0 ? 0 : (bidx > 9 ? 9 : bidx);

                float xlo = cx[0], xhi = cx[1], ylo = cy[0], yhi = cy[1];
                #pragma unroll
                for (int i = 1; i < 10; ++i) {
                    const bool pick = (i == ci);
                    xlo = pick ? cx[i]     : xlo;
                    xhi = pick ? cx[i + 1] : xhi;
                    ylo = pick ? cy[i]     : ylo;
                    yhi = pick ? cy[i + 1] : yhi;
                }
                const float xw = xhi - xlo, yw = yhi - ylo;
                const float rx = cx[10], ry = cy[10];

                // slopes: LDS-indexed read of the 2 needed raw params
                const float u1 = (float)R[t2][base + 20 + ci];
                const float u2 = (float)R[t2][base + 21 + ci];
                const float t1 = u1 * LOG2E;
                const float t2s = u2 * LOG2E;
                const float dd1 = PMIN_F + 0.999f * ((t1  > 15.f) ? t1  : flog2(1.f + fexp2(t1)));
                const float dd2 = PMIN_F + 0.999f * ((t2s > 15.f) ? t2s : flog2(1.f + fexp2(t2s)));

                const float xs  = inb ? x2 : (xlo + 0.5f * xw);
                const float rxw = frcp(xw);
                const float s   = yw * rxw;
                const float eta = (xs - xlo) * rxw;
                const float rev = 1.f - eta;
                const float er  = eta * rev;
                const float dn  = s + (dd1 + dd2 - 2.f * s) * er;
                const float yrq = ylo + yw * (s * eta * eta + dd1 * er) * frcp(dn);
                const float jn  = s * s * (dd2 * eta * eta + 2.f * s * er + dd1 * rev * rev);
                const float ljx = LN2 * (flog2(jn) - 2.f * flog2(dn));
                const float ylin = (ry + 1.f) * frcp(rx + 1.f) * (x2 + 1.f) - 1.f;

                xls[t2][row * 16 + 8 + d] = inb ? yrq : ylin;

                float lj = inb ? ljx : 0.f;
                lj += __shfl_xor(lj, 1);
                lj += __shfl_xor(lj, 2);
                ljrow[t2] += lj;
            }
            __syncthreads();
        }

        // ================= permutation =================
        {
            const int4 pv = ((const int4*)(perms + l * 16))[lane & 3];
            const int mm = lane >> 2;
            const float a0 = xls[0][mm * 16 + pv.x];
            const float a1v = xls[0][mm * 16 + pv.y];
            const float a2v = xls[0][mm * 16 + pv.z];
            const float a3v = xls[0][mm * 16 + pv.w];
            const float b0 = xls[1][mm * 16 + pv.x];
            const float b1v = xls[1][mm * 16 + pv.y];
            const float b2 = xls[1][mm * 16 + pv.z];
            const float b3 = xls[1][mm * 16 + pv.w];
            __syncthreads();
            *(float4*)&xls[0][lane * 4] = make_float4(a0, a1v, a2v, a3v);
            *(float4*)&xls[1][lane * 4] = make_float4(b0, b1v, b2, b3);
        }
        __syncthreads();
    }

    // ---- outputs: x [B,16] then ljd [B]
    #pragma unroll
    for (int t2 = 0; t2 < 2; ++t2) {
        const float4 vo = *(const float4*)&xls[t2][lane * 4];
        ((float4*)(out + (row0 + t2 * 16) * 16))[lane] = vo;
    }
    #pragma unroll
    for (int t2 = 0; t2 < 2; ++t2) {
        const float v = __shfl(ljrow[t2], (lane & 15) * 4);
        if (lane < 16)
            out[(size_t)B_N * 16 + row0 + t2 * 16 + lane] = v;
    }
}

extern "C" void kernel_launch(void* const* d_in, const int* in_sizes, int n_in,
                              void* d_out, int out_size, void* d_ws, size_t ws_size,
                              hipStream_t stream) {
    const float* x     = (const float*)d_in[0];
    const float* c     = (const float*)d_in[1];
    const float* W1s   = (const float*)d_in[2];
    const float* b1s   = (const float*)d_in[3];
    const float* Whs   = (const float*)d_in[4];
    const float* bhs   = (const float*)d_in[5];
    const float* Wos   = (const float*)d_in[6];
    const float* bos   = (const float*)d_in[7];
    const int*   perms = (const int*)d_in[8];
    float* out = (float*)d_out;
    _Float16* ws = (_Float16*)d_ws;

    prep_kernel<<<dim3(416), dim3(64), 0, stream>>>(W1s, b1s, Whs, Wos, ws);
    flow_mfma<<<dim3(B_N / 32), dim3(64), 0, stream>>>(
        x, c, bhs, bos, perms, ws, out);
}

// Round 10
// 301.504 us; speedup vs baseline: 1.1829x; 1.1829x over previous
//
#include <hip/hip_runtime.h>

#define B_N   262144
#define PMIN_F 0.001f
#define LOG2E 1.44269504088896340736f
#define LN2   0.69314718055994530942f

typedef _Float16 half4v __attribute__((ext_vector_type(4)));
typedef _Float16 half8  __attribute__((ext_vector_type(8)));
typedef float    floatx4 __attribute__((ext_vector_type(4)));

__device__ __forceinline__ float fexp2(float x) { return __builtin_amdgcn_exp2f(x); }
__device__ __forceinline__ float flog2(float x) { return __builtin_amdgcn_logf(x); }
__device__ __forceinline__ float frcp (float x) { return __builtin_amdgcn_rcpf(x); }

// ---------------------------------------------------------------------------
// Prep: weights fp32 -> f16 in MFMA B-fragment order (unchanged).
//   r in [0,8)   : mm1 W1 16x128, K padded to 32; k==16 row carries b1
//   r in [8,40)  : mm2 Wh 128x128
//   r in [40,104): mm3 Wo 128x248 column-remapped to 256 (31->32 pad per d)
// ---------------------------------------------------------------------------
__global__ __launch_bounds__(64) void prep_kernel(
    const float* __restrict__ W1s, const float* __restrict__ b1s,
    const float* __restrict__ Whs, const float* __restrict__ Wos,
    _Float16* __restrict__ ws)
{
    const int bid   = blockIdx.x;          // 0..415
    const int layer = bid / 104;
    const int r     = bid % 104;
    const int lane  = threadIdx.x;
    const int kg    = lane >> 4;
    const int c     = lane & 15;

    half8 v;
    if (r < 8) {
        const int nt = r, n = nt * 16 + c;
        const float* W1 = W1s + layer * 16 * 128;
        const float* b1 = b1s + layer * 128;
        #pragma unroll
        for (int j = 0; j < 8; ++j) {
            const int k = kg * 8 + j;
            v[j] = (k < 16) ? (_Float16)W1[k * 128 + n]
                 : (k == 16) ? (_Float16)b1[n] : (_Float16)0.f;
        }
    } else if (r < 40) {
        const int f = r - 8, nt = f >> 2, ks = f & 3, n = nt * 16 + c;
        const float* Wh = Whs + layer * 128 * 128;
        #pragma unroll
        for (int j = 0; j < 8; ++j) {
            const int k = ks * 32 + kg * 8 + j;
            v[j] = (_Float16)Wh[k * 128 + n];
        }
    } else {
        const int f = r - 40, nt = f >> 2, ks = f & 3, n = nt * 16 + c;
        const int dd = n >> 5, cc = n & 31;
        const float* Wo = Wos + layer * 128 * 248;
        #pragma unroll
        for (int j = 0; j < 8; ++j) {
            const int k = ks * 32 + kg * 8 + j;
            v[j] = (cc < 31) ? (_Float16)Wo[k * 248 + dd * 31 + cc] : (_Float16)0.f;
        }
    }
    *(half8*)(ws + (size_t)bid * 512 + lane * 8) = v;
}

// ---------------------------------------------------------------------------
// Main: one wave = 32 rows (2 tiles). MFMA in nt-groups of 4 -> peak 32 AGPR.
// Register model (R2/R5..R9-validated): __launch_bounds__(64,N) PINS arch
// VGPR at 512/(2N) when MFMA/AGPRs are in use: N=4 -> arch=64 (spills if
// need>64). N=3 -> allocator free up to need (~64-76). HW occupancy =
// 512/(arch+AGPR); lower actual need -> more waves. So: keep N=3 and shrink
// register need instead (streaming spline scans, no cx/cy arrays).
// LDS/WG = 2KB xls + 8.25KB R = 10.25KB -> 14-15 WGs/CU (not binding to ~44%).
// ---------------------------------------------------------------------------
__global__ __launch_bounds__(64, 3) void flow_mfma(
    const float* __restrict__ x_in,
    const float* __restrict__ c_in,
    const float* __restrict__ bhs,
    const float* __restrict__ bos,
    const int*   __restrict__ perms,
    const _Float16* __restrict__ wsW,
    float* __restrict__ out)
{
    __shared__ __align__(16) float    xls[2][256];   // [tile][16 rows][16]
    __shared__ __align__(16) _Float16 R[2][2112];    // h1 / h2 / theta-half, stride 132

    const int lane = threadIdx.x;
    const int q    = lane >> 4;
    const int m    = lane & 15;
    const long long row0 = (long long)blockIdx.x * 32;

    {
        const float4* xp = (const float4*)(x_in + row0 * 16);
        *(float4*)&xls[0][lane * 4] = xp[lane];
        *(float4*)&xls[1][lane * 4] = xp[lane + 64];
    }

    // layer-invariant part of the mm1 A-fragment (c data / bias-one).
    half8 a1c[2];
    #pragma unroll
    for (int t2 = 0; t2 < 2; ++t2) {
        #pragma unroll
        for (int j = 0; j < 8; ++j) a1c[t2][j] = (_Float16)0.f;
        if (q == 1) {
            const float4* cp = (const float4*)(c_in + (row0 + t2 * 16 + m) * 8);
            const float4 c0 = cp[0], c1 = cp[1];
            a1c[t2][0] = (_Float16)c0.x; a1c[t2][1] = (_Float16)c0.y;
            a1c[t2][2] = (_Float16)c0.z; a1c[t2][3] = (_Float16)c0.w;
            a1c[t2][4] = (_Float16)c1.x; a1c[t2][5] = (_Float16)c1.y;
            a1c[t2][6] = (_Float16)c1.z; a1c[t2][7] = (_Float16)c1.w;
        } else if (q == 2) {
            a1c[t2][0] = (_Float16)1.f;   // k=16 -> bias row
        }
    }
    __syncthreads();

    float ljrow[2] = {0.f, 0.f};

    for (int l = 0; l < 4; ++l) {
        const _Float16* wsl = wsW + (size_t)l * 104 * 512;
        const float* bh = bhs + l * 128;
        const float* bo = bos + l * 248;

        // ================= mm1: [x1,c,1] @ [W1;b1] -> h1 =================
        half8 a1[2];
        #pragma unroll
        for (int t2 = 0; t2 < 2; ++t2) {
            a1[t2] = a1c[t2];
            if (q == 0) {
                const float4 lo = *(const float4*)&xls[t2][m * 16];
                const float4 hi = *(const float4*)&xls[t2][m * 16 + 4];
                a1[t2][0] = (_Float16)lo.x; a1[t2][1] = (_Float16)lo.y;
                a1[t2][2] = (_Float16)lo.z; a1[t2][3] = (_Float16)lo.w;
                a1[t2][4] = (_Float16)hi.x; a1[t2][5] = (_Float16)hi.y;
                a1[t2][6] = (_Float16)hi.z; a1[t2][7] = (_Float16)hi.w;
            }
        }
        #pragma unroll
        for (int g = 0; g < 2; ++g) {
            const floatx4 z = {0.f, 0.f, 0.f, 0.f};
            floatx4 acc0[4], acc1[4];
            #pragma unroll
            for (int nt = 0; nt < 4; ++nt) {
                const half8 b = *(const half8*)(wsl + (g * 4 + nt) * 512 + lane * 8);
                acc0[nt] = __builtin_amdgcn_mfma_f32_16x16x32_f16(a1[0], b, z, 0, 0, 0);
                acc1[nt] = __builtin_amdgcn_mfma_f32_16x16x32_f16(a1[1], b, z, 0, 0, 0);
            }
            #pragma unroll
            for (int nt = 0; nt < 4; ++nt)
                #pragma unroll
                for (int reg = 0; reg < 4; ++reg) {
                    R[0][(q * 4 + reg) * 132 + (g * 4 + nt) * 16 + m] = (_Float16)fmaxf(acc0[nt][reg], 0.f);
                    R[1][(q * 4 + reg) * 132 + (g * 4 + nt) * 16 + m] = (_Float16)fmaxf(acc1[nt][reg], 0.f);
                }
        }
        __syncthreads();

        // ===== mm2: pull h1 A-frags to regs, then overwrite region with h2 =====
        half8 a2[2][4];
        #pragma unroll
        for (int t2 = 0; t2 < 2; ++t2)
            #pragma unroll
            for (int ks = 0; ks < 4; ++ks) {
                const half4v lo = *(const half4v*)&R[t2][m * 132 + ks * 32 + q * 8];
                const half4v hi = *(const half4v*)&R[t2][m * 132 + ks * 32 + q * 8 + 4];
                a2[t2][ks] = __builtin_shufflevector(lo, hi, 0, 1, 2, 3, 4, 5, 6, 7);
            }
        __syncthreads();
        #pragma unroll
        for (int g = 0; g < 2; ++g) {
            floatx4 acc0[4], acc1[4];
            #pragma unroll
            for (int nt = 0; nt < 4; ++nt) {
                const float bb = bh[(g * 4 + nt) * 16 + m];
                acc0[nt][0] = bb; acc0[nt][1] = bb; acc0[nt][2] = bb; acc0[nt][3] = bb;
                acc1[nt] = acc0[nt];
            }
            #pragma unroll
            for (int ks = 0; ks < 4; ++ks)
                #pragma unroll
                for (int nt = 0; nt < 4; ++nt) {
                    const half8 b = *(const half8*)(wsl + (8 + (g * 4 + nt) * 4 + ks) * 512 + lane * 8);
                    acc0[nt] = __builtin_amdgcn_mfma_f32_16x16x32_f16(a2[0][ks], b, acc0[nt], 0, 0, 0);
                    acc1[nt] = __builtin_amdgcn_mfma_f32_16x16x32_f16(a2[1][ks], b, acc1[nt], 0, 0, 0);
                }
            #pragma unroll
            for (int nt = 0; nt < 4; ++nt)
                #pragma unroll
                for (int reg = 0; reg < 4; ++reg) {
                    R[0][(q * 4 + reg) * 132 + (g * 4 + nt) * 16 + m] = (_Float16)fmaxf(acc0[nt][reg], 0.f);
                    R[1][(q * 4 + reg) * 132 + (g * 4 + nt) * 16 + m] = (_Float16)fmaxf(acc1[nt][reg], 0.f);
                }
        }
        __syncthreads();

        // ===== mm3: pull h2 A-frags to regs; theta halves overwrite region =====
        half8 a3[2][4];
        #pragma unroll
        for (int t2 = 0; t2 < 2; ++t2)
            #pragma unroll
            for (int ks = 0; ks < 4; ++ks) {
                const half4v lo = *(const half4v*)&R[t2][m * 132 + ks * 32 + q * 8];
                const half4v hi = *(const half4v*)&R[t2][m * 132 + ks * 32 + q * 8 + 4];
                a3[t2][ks] = __builtin_shufflevector(lo, hi, 0, 1, 2, 3, 4, 5, 6, 7);
            }
        __syncthreads();

        #pragma unroll
        for (int hf = 0; hf < 2; ++hf) {
            // ---- mm3 half: cols [hf*128, hf*128+128) = d in [hf*4, hf*4+4)
            #pragma unroll
            for (int g = 0; g < 2; ++g) {
                floatx4 acc0[4], acc1[4];
                #pragma unroll
                for (int nt4 = 0; nt4 < 4; ++nt4) {
                    const int nt = hf * 8 + g * 4 + nt4;
                    const float bb = ((nt & 1) && m == 15) ? 0.f
                                   : bo[(nt >> 1) * 31 + (nt & 1) * 16 + m];
                    acc0[nt4][0] = bb; acc0[nt4][1] = bb; acc0[nt4][2] = bb; acc0[nt4][3] = bb;
                    acc1[nt4] = acc0[nt4];
                }
                #pragma unroll
                for (int ks = 0; ks < 4; ++ks)
                    #pragma unroll
                    for (int nt4 = 0; nt4 < 4; ++nt4) {
                        const int nt = hf * 8 + g * 4 + nt4;
                        const half8 b = *(const half8*)(wsl + (40 + nt * 4 + ks) * 512 + lane * 8);
                        acc0[nt4] = __builtin_amdgcn_mfma_f32_16x16x32_f16(a3[0][ks], b, acc0[nt4], 0, 0, 0);
                        acc1[nt4] = __builtin_amdgcn_mfma_f32_16x16x32_f16(a3[1][ks], b, acc1[nt4], 0, 0, 0);
                    }
                #pragma unroll
                for (int nt4 = 0; nt4 < 4; ++nt4)
                    #pragma unroll
                    for (int reg = 0; reg < 4; ++reg) {
                        R[0][(q * 4 + reg) * 132 + (g * 4 + nt4) * 16 + m] = (_Float16)acc0[nt4][reg];
                        R[1][(q * 4 + reg) * 132 + (g * 4 + nt4) * 16 + m] = (_Float16)acc1[nt4][reg];
                    }
            }
            __syncthreads();

            // ---- spline half-pass: 128 items (2 tiles x 16 rows x 4 d) ----
            // Streaming scans: no cx[]/cy[] arrays (register diet).
            #pragma unroll
            for (int itp = 0; itp < 2; ++itp) {
                const int t2   = itp;
                const int row  = lane >> 2;
                const int dloc = lane & 3;
                const int d    = hf * 4 + dloc;
                const int base = row * 132 + dloc * 32;

                const half4v v0 = *(const half4v*)&R[t2][base];
                const half4v v1 = *(const half4v*)&R[t2][base + 4];
                const half4v v2 = *(const half4v*)&R[t2][base + 8];
                const half4v v3 = *(const half4v*)&R[t2][base + 12];
                const half4v v4 = *(const half4v*)&R[t2][base + 16];
                const float x2 = xls[t2][row * 16 + 8 + d];

                // widths: exp values kept in tw[] (needed for 2 passes)
                float tw[10];
                tw[0]=(float)v0[0]; tw[1]=(float)v0[1]; tw[2]=(float)v0[2]; tw[3]=(float)v0[3];
                tw[4]=(float)v1[0]; tw[5]=(float)v1[1]; tw[6]=(float)v1[2]; tw[7]=(float)v1[3];
                tw[8]=(float)v2[0]; tw[9]=(float)v2[1];
                float m1 = tw[0];
                #pragma unroll
                for (int i = 1; i < 10; ++i) m1 = fmaxf(m1, tw[i]);
                float se = 0.f;
                #pragma unroll
                for (int i = 0; i < 10; ++i) { tw[i] = fexp2((tw[i] - m1) * LOG2E); se += tw[i]; }
                const float inv198 = 1.98f * frcp(se);   // 2*(1-PMIN*K)/sum

                // pass 1: bin count (no array)
                int cnt = 0;
                {
                    float run = -1.f;
                    cnt += (run < x2) ? 1 : 0;
                    #pragma unroll
                    for (int i = 0; i < 10; ++i) {
                        run = run + fmaf(tw[i], inv198, 0.002f);
                        cnt += (run < x2) ? 1 : 0;
                    }
                }
                const int bidx = cnt - 1;
                const bool inb = (bidx >= 0) && (bidx < 10);
                const int ci = bidx < 0 ? 0 : (bidx > 9 ? 9 : bidx);

                // pass 2: recompute cumsum, select xlo/xhi on the fly
                float xlo = -1.f, xhi = 0.f, rx;
                {
                    float run = -1.f;
                    #pragma unroll
                    for (int i = 0; i < 10; ++i) {
                        const bool pick = (i == ci);
                        xlo = pick ? run : xlo;
                        run = run + fmaf(tw[i], inv198, 0.002f);
                        xhi = pick ? run : xhi;
                    }
                    rx = run;
                }

                // heights: single streaming pass (convert from packed halves
                // twice; no array)
                float hm;
                {
                    const float h0=(float)v2[2], h1=(float)v2[3];
                    const float h2=(float)v3[0], h3=(float)v3[1];
                    const float h4=(float)v3[2], h5=(float)v3[3];
                    const float h6=(float)v4[0], h7=(float)v4[1];
                    const float h8=(float)v4[2], h9=(float)v4[3];
                    hm = fmaxf(fmaxf(fmaxf(h0,h1),fmaxf(h2,h3)),
                               fmaxf(fmaxf(h4,h5),fmaxf(fmaxf(h6,h7),fmaxf(h8,h9))));
                }
                float seh = 0.f;
                {
                    seh += fexp2(((float)v2[2] - hm) * LOG2E);
                    seh += fexp2(((float)v2[3] - hm) * LOG2E);
                    seh += fexp2(((float)v3[0] - hm) * LOG2E);
                    seh += fexp2(((float)v3[1] - hm) * LOG2E);
                    seh += fexp2(((float)v3[2] - hm) * LOG2E);
                    seh += fexp2(((float)v3[3] - hm) * LOG2E);
                    seh += fexp2(((float)v4[0] - hm) * LOG2E);
                    seh += fexp2(((float)v4[1] - hm) * LOG2E);
                    seh += fexp2(((float)v4[2] - hm) * LOG2E);
                    seh += fexp2(((float)v4[3] - hm) * LOG2E);
                }
                const float invh = 1.98f * frcp(seh);
                float ylo = -1.f, yhi = 0.f, ry;
                {
                    float run = -1.f;
                    #pragma unroll
                    for (int i = 0; i < 10; ++i) {
                        const float hv = (i < 2) ? (float)v2[2 + i]
                                      : (i < 6) ? (float)v3[i - 2]
                                                : (float)v4[i - 6];
                        const float e = fexp2((hv - hm) * LOG2E);
                        const bool pick = (i == ci);
                        ylo = pick ? run : ylo;
                        run = run + fmaf(e, invh, 0.002f);
                        yhi = pick ? run : yhi;
                    }
                    ry = run;
                }

                const float xw = xhi - xlo, yw = yhi - ylo;

                // slopes: LDS-indexed read of the 2 needed raw params
                const float u1 = (float)R[t2][base + 20 + ci];
                const float u2 = (float)R[t2][base + 21 + ci];
                const float t1 = u1 * LOG2E;
                const float t2s = u2 * LOG2E;
                const float dd1 = PMIN_F + 0.999f * ((t1  > 15.f) ? t1  : flog2(1.f + fexp2(t1)));
                const float dd2 = PMIN_F + 0.999f * ((t2s > 15.f) ? t2s : flog2(1.f + fexp2(t2s)));

                const float xs  = inb ? x2 : (xlo + 0.5f * xw);
                const float rxw = frcp(xw);
                const float s   = yw * rxw;
                const float eta = (xs - xlo) * rxw;
                const float rev = 1.f - eta;
                const float er  = eta * rev;
                const float dn  = s + (dd1 + dd2 - 2.f * s) * er;
                const float yrq = ylo + yw * (s * eta * eta + dd1 * er) * frcp(dn);
                const float jn  = s * s * (dd2 * eta * eta + 2.f * s * er + dd1 * rev * rev);
                const float ljx = LN2 * (flog2(jn) - 2.f * flog2(dn));
                const float ylin = (ry + 1.f) * frcp(rx + 1.f) * (x2 + 1.f) - 1.f;

                xls[t2][row * 16 + 8 + d] = inb ? yrq : ylin;

                float lj = inb ? ljx : 0.f;
                lj += __shfl_xor(lj, 1);
                lj += __shfl_xor(lj, 2);
                ljrow[t2] += lj;
            }
            __syncthreads();
        }

        // ================= permutation =================
        {
            const int4 pv = ((const int4*)(perms + l * 16))[lane & 3];
            const int mm = lane >> 2;
            const float a0 = xls[0][mm * 16 + pv.x];
            const float a1v = xls[0][mm * 16 + pv.y];
            const float a2v = xls[0][mm * 16 + pv.z];
            const float a3v = xls[0][mm * 16 + pv.w];
            const float b0 = xls[1][mm * 16 + pv.x];
            const float b1v = xls[1][mm * 16 + pv.y];
            const float b2 = xls[1][mm * 16 + pv.z];
            const float b3 = xls[1][mm * 16 + pv.w];
            __syncthreads();
            *(float4*)&xls[0][lane * 4] = make_float4(a0, a1v, a2v, a3v);
            *(float4*)&xls[1][lane * 4] = make_float4(b0, b1v, b2, b3);
        }
        __syncthreads();
    }

    // ---- outputs: x [B,16] then ljd [B]
    #pragma unroll
    for (int t2 = 0; t2 < 2; ++t2) {
        const float4 vo = *(const float4*)&xls[t2][lane * 4];
        ((float4*)(out + (row0 + t2 * 16) * 16))[lane] = vo;
    }
    #pragma unroll
    for (int t2 = 0; t2 < 2; ++t2) {
        const float v = __shfl(ljrow[t2], (lane & 15) * 4);
        if (lane < 16)
            out[(size_t)B_N * 16 + row0 + t2 * 16 + lane] = v;
    }
}

extern "C" void kernel_launch(void* const* d_in, const int* in_sizes, int n_in,
                              void* d_out, int out_size, void* d_ws, size_t ws_size,
                              hipStream_t stream) {
    const float* x     = (const float*)d_in[0];
    const float* c     = (const float*)d_in[1];
    const float* W1s   = (const float*)d_in[2];
    const float* b1s   = (const float*)d_in[3];
    const float* Whs   = (const float*)d_in[4];
    const float* bhs   = (const float*)d_in[5];
    const float* Wos   = (const float*)d_in[6];
    const float* bos   = (const float*)d_in[7];
    const int*   perms = (const int*)d_in[8];
    float* out = (float*)d_out;
    _Float16* ws = (_Float16*)d_ws;

    prep_kernel<<<dim3(416), dim3(64), 0, stream>>>(W1s, b1s, Whs, Wos, ws);
    flow_mfma<<<dim3(B_N / 32), dim3(64), 0, stream>>>(
        x, c, bhs, bos, perms, ws, out);
}

// Round 11
// 281.038 us; speedup vs baseline: 1.2690x; 1.0728x over previous
//
#include <hip/hip_runtime.h>

#define B_N   262144
#define PMIN_F 0.001f
#define LOG2E 1.44269504088896340736f
#define LN2   0.69314718055994530942f

typedef _Float16 half4v __attribute__((ext_vector_type(4)));
typedef _Float16 half8  __attribute__((ext_vector_type(8)));
typedef float    floatx4 __attribute__((ext_vector_type(4)));

__device__ __forceinline__ float fexp2(float x) { return __builtin_amdgcn_exp2f(x); }
__device__ __forceinline__ float flog2(float x) { return __builtin_amdgcn_logf(x); }
__device__ __forceinline__ float frcp (float x) { return __builtin_amdgcn_rcpf(x); }

// ---------------------------------------------------------------------------
// Prep: weights fp32 -> f16 in MFMA B-fragment order (unchanged).
//   r in [0,8)   : mm1 W1 16x128, K padded to 32; k==16 row carries b1
//   r in [8,40)  : mm2 Wh 128x128
//   r in [40,104): mm3 Wo 128x248 column-remapped to 256 (31->32 pad per d)
// ---------------------------------------------------------------------------
__global__ __launch_bounds__(64) void prep_kernel(
    const float* __restrict__ W1s, const float* __restrict__ b1s,
    const float* __restrict__ Whs, const float* __restrict__ Wos,
    _Float16* __restrict__ ws)
{
    const int bid   = blockIdx.x;          // 0..415
    const int layer = bid / 104;
    const int r     = bid % 104;
    const int lane  = threadIdx.x;
    const int kg    = lane >> 4;
    const int c     = lane & 15;

    half8 v;
    if (r < 8) {
        const int nt = r, n = nt * 16 + c;
        const float* W1 = W1s + layer * 16 * 128;
        const float* b1 = b1s + layer * 128;
        #pragma unroll
        for (int j = 0; j < 8; ++j) {
            const int k = kg * 8 + j;
            v[j] = (k < 16) ? (_Float16)W1[k * 128 + n]
                 : (k == 16) ? (_Float16)b1[n] : (_Float16)0.f;
        }
    } else if (r < 40) {
        const int f = r - 8, nt = f >> 2, ks = f & 3, n = nt * 16 + c;
        const float* Wh = Whs + layer * 128 * 128;
        #pragma unroll
        for (int j = 0; j < 8; ++j) {
            const int k = ks * 32 + kg * 8 + j;
            v[j] = (_Float16)Wh[k * 128 + n];
        }
    } else {
        const int f = r - 40, nt = f >> 2, ks = f & 3, n = nt * 16 + c;
        const int dd = n >> 5, cc = n & 31;
        const float* Wo = Wos + layer * 128 * 248;
        #pragma unroll
        for (int j = 0; j < 8; ++j) {
            const int k = ks * 32 + kg * 8 + j;
            v[j] = (cc < 31) ? (_Float16)Wo[k * 248 + dd * 31 + cc] : (_Float16)0.f;
        }
    }
    *(half8*)(ws + (size_t)bid * 512 + lane * 8) = v;
}

// ---------------------------------------------------------------------------
// Main: one wave = 32 rows (2 tiles). Single-wave WG => LDS pipe is in-order
// per wave; __syncthreads() is NOT needed for correctness, only as a compiler
// fence across the f16(h) / f32(theta) type-punned overlay. We keep exactly 2
// barriers per layer (after a3 f16 pull; at layer end) and drop the other 8
// so the scheduler can overlap MFMA / global loads / spline VALU.
// Theta is stored as f32 (no cvt on store, none on spline read); mm3 runs in
// 4 quarter-passes (64 cols) so f32 theta fits the same R region.
// R per tile: h as f16 rows stride 132 (2112 halves); theta as f32 rows
// stride 68 (1088 f32 = 2176 halves). R[2][2176] = 8704 B; +xls 2 KB = 10752.
// Register model (R2/R5..R10): launch_bounds (64,N) pins arch=512/(2N) at
// N>=4 (spill); N=3 leaves allocator free (~76 arch + 32 AGPR).
// ---------------------------------------------------------------------------
__global__ __launch_bounds__(64, 3) void flow_mfma(
    const float* __restrict__ x_in,
    const float* __restrict__ c_in,
    const float* __restrict__ bhs,
    const float* __restrict__ bos,
    const int*   __restrict__ perms,
    const _Float16* __restrict__ wsW,
    float* __restrict__ out)
{
    __shared__ __align__(16) float    xls[2][256];   // [tile][16 rows][16]
    __shared__ __align__(16) _Float16 R[2][2176];    // h(f16,132) / theta(f32,68)

    const int lane = threadIdx.x;
    const int q    = lane >> 4;
    const int m    = lane & 15;
    const long long row0 = (long long)blockIdx.x * 32;

    {
        const float4* xp = (const float4*)(x_in + row0 * 16);
        *(float4*)&xls[0][lane * 4] = xp[lane];
        *(float4*)&xls[1][lane * 4] = xp[lane + 64];
    }

    // layer-invariant part of the mm1 A-fragment (c data / bias-one)
    half8 a1c[2];
    #pragma unroll
    for (int t2 = 0; t2 < 2; ++t2) {
        #pragma unroll
        for (int j = 0; j < 8; ++j) a1c[t2][j] = (_Float16)0.f;
        if (q == 1) {
            const float4* cp = (const float4*)(c_in + (row0 + t2 * 16 + m) * 8);
            const float4 c0 = cp[0], c1 = cp[1];
            a1c[t2][0] = (_Float16)c0.x; a1c[t2][1] = (_Float16)c0.y;
            a1c[t2][2] = (_Float16)c0.z; a1c[t2][3] = (_Float16)c0.w;
            a1c[t2][4] = (_Float16)c1.x; a1c[t2][5] = (_Float16)c1.y;
            a1c[t2][6] = (_Float16)c1.z; a1c[t2][7] = (_Float16)c1.w;
        } else if (q == 2) {
            a1c[t2][0] = (_Float16)1.f;   // k=16 -> bias row
        }
    }

    // spline item mapping (fixed per lane): tile, row, d-parity
    const int sp_t2  = lane >> 5;
    const int sp_row = (lane & 31) >> 1;
    const int sp_dl  = lane & 1;

    float ljacc = 0.f;

    for (int l = 0; l < 4; ++l) {
        const _Float16* wsl = wsW + (size_t)l * 104 * 512;
        const float* bh = bhs + l * 128;
        const float* bo = bos + l * 248;

        // ================= mm1: [x1,c,1] @ [W1;b1] -> h1 (f16) =============
        half8 a1[2];
        #pragma unroll
        for (int t2 = 0; t2 < 2; ++t2) {
            a1[t2] = a1c[t2];
            if (q == 0) {
                const float4 lo = *(const float4*)&xls[t2][m * 16];
                const float4 hi = *(const float4*)&xls[t2][m * 16 + 4];
                a1[t2][0] = (_Float16)lo.x; a1[t2][1] = (_Float16)lo.y;
                a1[t2][2] = (_Float16)lo.z; a1[t2][3] = (_Float16)lo.w;
                a1[t2][4] = (_Float16)hi.x; a1[t2][5] = (_Float16)hi.y;
                a1[t2][6] = (_Float16)hi.z; a1[t2][7] = (_Float16)hi.w;
            }
        }
        #pragma unroll
        for (int g = 0; g < 2; ++g) {
            const floatx4 z = {0.f, 0.f, 0.f, 0.f};
            floatx4 acc0[4], acc1[4];
            #pragma unroll
            for (int nt = 0; nt < 4; ++nt) {
                const half8 b = *(const half8*)(wsl + (g * 4 + nt) * 512 + lane * 8);
                acc0[nt] = __builtin_amdgcn_mfma_f32_16x16x32_f16(a1[0], b, z, 0, 0, 0);
                acc1[nt] = __builtin_amdgcn_mfma_f32_16x16x32_f16(a1[1], b, z, 0, 0, 0);
            }
            #pragma unroll
            for (int nt = 0; nt < 4; ++nt)
                #pragma unroll
                for (int reg = 0; reg < 4; ++reg) {
                    R[0][(q * 4 + reg) * 132 + (g * 4 + nt) * 16 + m] = (_Float16)fmaxf(acc0[nt][reg], 0.f);
                    R[1][(q * 4 + reg) * 132 + (g * 4 + nt) * 16 + m] = (_Float16)fmaxf(acc1[nt][reg], 0.f);
                }
        }

        // ===== mm2: pull h1 A-frags (in-order LDS, no barrier needed) ======
        half8 a2[2][4];
        #pragma unroll
        for (int t2 = 0; t2 < 2; ++t2)
            #pragma unroll
            for (int ks = 0; ks < 4; ++ks) {
                const half4v lo = *(const half4v*)&R[t2][m * 132 + ks * 32 + q * 8];
                const half4v hi = *(const half4v*)&R[t2][m * 132 + ks * 32 + q * 8 + 4];
                a2[t2][ks] = __builtin_shufflevector(lo, hi, 0, 1, 2, 3, 4, 5, 6, 7);
            }
        #pragma unroll
        for (int g = 0; g < 2; ++g) {
            floatx4 acc0[4], acc1[4];
            #pragma unroll
            for (int nt = 0; nt < 4; ++nt) {
                const float bb = bh[(g * 4 + nt) * 16 + m];
                acc0[nt][0] = bb; acc0[nt][1] = bb; acc0[nt][2] = bb; acc0[nt][3] = bb;
                acc1[nt] = acc0[nt];
            }
            #pragma unroll
            for (int ks = 0; ks < 4; ++ks)
                #pragma unroll
                for (int nt = 0; nt < 4; ++nt) {
                    const half8 b = *(const half8*)(wsl + (8 + (g * 4 + nt) * 4 + ks) * 512 + lane * 8);
                    acc0[nt] = __builtin_amdgcn_mfma_f32_16x16x32_f16(a2[0][ks], b, acc0[nt], 0, 0, 0);
                    acc1[nt] = __builtin_amdgcn_mfma_f32_16x16x32_f16(a2[1][ks], b, acc1[nt], 0, 0, 0);
                }
            #pragma unroll
            for (int nt = 0; nt < 4; ++nt)
                #pragma unroll
                for (int reg = 0; reg < 4; ++reg) {
                    R[0][(q * 4 + reg) * 132 + (g * 4 + nt) * 16 + m] = (_Float16)fmaxf(acc0[nt][reg], 0.f);
                    R[1][(q * 4 + reg) * 132 + (g * 4 + nt) * 16 + m] = (_Float16)fmaxf(acc1[nt][reg], 0.f);
                }
        }

        // ===== mm3: pull h2 A-frags to regs ===============================
        half8 a3[2][4];
        #pragma unroll
        for (int t2 = 0; t2 < 2; ++t2)
            #pragma unroll
            for (int ks = 0; ks < 4; ++ks) {
                const half4v lo = *(const half4v*)&R[t2][m * 132 + ks * 32 + q * 8];
                const half4v hi = *(const half4v*)&R[t2][m * 132 + ks * 32 + q * 8 + 4];
                a3[t2][ks] = __builtin_shufflevector(lo, hi, 0, 1, 2, 3, 4, 5, 6, 7);
            }
        __syncthreads();   // FENCE: f16 h-reads above vs f32 theta-writes below

        float* Rf0 = (float*)&R[0][0];
        float* Rf1 = (float*)&R[1][0];

        #pragma unroll
        for (int qd = 0; qd < 4; ++qd) {
            // ---- mm3 quarter: cols [qd*64, qd*64+64) = d in {qd*2, qd*2+1}
            {
                floatx4 acc0[4], acc1[4];
                #pragma unroll
                for (int j = 0; j < 4; ++j) {
                    const int n = qd * 64 + j * 16 + m;
                    const int cc = n & 31;
                    const float bb = (cc < 31) ? bo[(n >> 5) * 31 + cc] : 0.f;
                    acc0[j][0] = bb; acc0[j][1] = bb; acc0[j][2] = bb; acc0[j][3] = bb;
                    acc1[j] = acc0[j];
                }
                #pragma unroll
                for (int ks = 0; ks < 4; ++ks)
                    #pragma unroll
                    for (int j = 0; j < 4; ++j) {
                        const int nt = qd * 4 + j;
                        const half8 b = *(const half8*)(wsl + (40 + nt * 4 + ks) * 512 + lane * 8);
                        acc0[j] = __builtin_amdgcn_mfma_f32_16x16x32_f16(a3[0][ks], b, acc0[j], 0, 0, 0);
                        acc1[j] = __builtin_amdgcn_mfma_f32_16x16x32_f16(a3[1][ks], b, acc1[j], 0, 0, 0);
                    }
                // store theta as f32: addr = row*68 + (j>>1)*32 + ((j&1)*16+m)
                #pragma unroll
                for (int j = 0; j < 4; ++j) {
                    const int off = (j >> 1) * 32 + (j & 1) * 16 + m;
                    #pragma unroll
                    for (int reg = 0; reg < 4; ++reg) {
                        Rf0[(q * 4 + reg) * 68 + off] = acc0[j][reg];
                        Rf1[(q * 4 + reg) * 68 + off] = acc1[j][reg];
                    }
                }
            }

            // ---- spline quarter: 64 items, 1/lane: (sp_t2, sp_row, d) -----
            {
                const int d    = qd * 2 + sp_dl;
                const int base = sp_row * 68 + sp_dl * 32;
                const float* Rf = sp_t2 ? Rf1 : Rf0;

                const float4 v0 = *(const float4*)&Rf[base];
                const float4 v1 = *(const float4*)&Rf[base + 4];
                const float4 v2 = *(const float4*)&Rf[base + 8];
                const float4 v3 = *(const float4*)&Rf[base + 12];
                const float4 v4 = *(const float4*)&Rf[base + 16];
                const float x2 = xls[sp_t2][sp_row * 16 + 8 + d];

                float tw[10] = {v0.x, v0.y, v0.z, v0.w, v1.x, v1.y, v1.z, v1.w, v2.x, v2.y};
                float m1 = tw[0];
                #pragma unroll
                for (int i = 1; i < 10; ++i) m1 = fmaxf(m1, tw[i]);
                float se = 0.f;
                #pragma unroll
                for (int i = 0; i < 10; ++i) { tw[i] = fexp2((tw[i] - m1) * LOG2E); se += tw[i]; }
                const float inv198 = 1.98f * frcp(se);   // 2*(1-PMIN*K)/sum

                int cnt = 0;
                {
                    float run = -1.f;
                    cnt += (run < x2) ? 1 : 0;
                    #pragma unroll
                    for (int i = 0; i < 10; ++i) {
                        run = run + fmaf(tw[i], inv198, 0.002f);
                        cnt += (run < x2) ? 1 : 0;
                    }
                }
                const int bidx = cnt - 1;
                const bool inb = (bidx >= 0) && (bidx < 10);
                const int ci = bidx < 0 ? 0 : (bidx > 9 ? 9 : bidx);

                float xlo = -1.f, xhi = 0.f, rx;
                {
                    float run = -1.f;
                    #pragma unroll
                    for (int i = 0; i < 10; ++i) {
                        const bool pick = (i == ci);
                        xlo = pick ? run : xlo;
                        run = run + fmaf(tw[i], inv198, 0.002f);
                        xhi = pick ? run : xhi;
                    }
                    rx = run;
                }

                float hh[10] = {v2.z, v2.w, v3.x, v3.y, v3.z, v3.w, v4.x, v4.y, v4.z, v4.w};
                float hm = hh[0];
                #pragma unroll
                for (int i = 1; i < 10; ++i) hm = fmaxf(hm, hh[i]);
                float seh = 0.f;
                #pragma unroll
                for (int i = 0; i < 10; ++i) { hh[i] = fexp2((hh[i] - hm) * LOG2E); seh += hh[i]; }
                const float invh = 1.98f * frcp(seh);
                float ylo = -1.f, yhi = 0.f, ry;
                {
                    float run = -1.f;
                    #pragma unroll
                    for (int i = 0; i < 10; ++i) {
                        const bool pick = (i == ci);
                        ylo = pick ? run : ylo;
                        run = run + fmaf(hh[i], invh, 0.002f);
                        yhi = pick ? run : yhi;
                    }
                    ry = run;
                }

                const float xw = xhi - xlo, yw = yhi - ylo;

                const float u1 = Rf[base + 20 + ci];
                const float u2 = Rf[base + 21 + ci];
                const float t1 = u1 * LOG2E;
                const float t2s = u2 * LOG2E;
                const float dd1 = PMIN_F + 0.999f * ((t1  > 15.f) ? t1  : flog2(1.f + fexp2(t1)));
                const float dd2 = PMIN_F + 0.999f * ((t2s > 15.f) ? t2s : flog2(1.f + fexp2(t2s)));

                const float xs  = inb ? x2 : (xlo + 0.5f * xw);
                const float rxw = frcp(xw);
                const float s   = yw * rxw;
                const float eta = (xs - xlo) * rxw;
                const float rev = 1.f - eta;
                const float er  = eta * rev;
                const float dn  = s + (dd1 + dd2 - 2.f * s) * er;
                const float yrq = ylo + yw * (s * eta * eta + dd1 * er) * frcp(dn);
                const float jn  = s * s * (dd2 * eta * eta + 2.f * s * er + dd1 * rev * rev);
                const float ljx = LN2 * (flog2(jn) - 2.f * flog2(dn));
                const float ylin = (ry + 1.f) * frcp(rx + 1.f) * (x2 + 1.f) - 1.f;

                xls[sp_t2][sp_row * 16 + 8 + d] = inb ? yrq : ylin;
                ljacc += inb ? ljx : 0.f;
            }
        }

        // ================= permutation (in-order LDS, same-type) ===========
        {
            const int4 pv = ((const int4*)(perms + l * 16))[lane & 3];
            const int mm = lane >> 2;
            const float a0 = xls[0][mm * 16 + pv.x];
            const float a1v = xls[0][mm * 16 + pv.y];
            const float a2v = xls[0][mm * 16 + pv.z];
            const float a3v = xls[0][mm * 16 + pv.w];
            const float b0 = xls[1][mm * 16 + pv.x];
            const float b1v = xls[1][mm * 16 + pv.y];
            const float b2 = xls[1][mm * 16 + pv.z];
            const float b3 = xls[1][mm * 16 + pv.w];
            *(float4*)&xls[0][lane * 4] = make_float4(a0, a1v, a2v, a3v);
            *(float4*)&xls[1][lane * 4] = make_float4(b0, b1v, b2, b3);
        }
        __syncthreads();   // FENCE: f32 theta-reads this layer vs f16 h-writes next
    }

    // ---- outputs: x [B,16] then ljd [B]
    #pragma unroll
    for (int t2 = 0; t2 < 2; ++t2) {
        const float4 vo = *(const float4*)&xls[t2][lane * 4];
        ((float4*)(out + (row0 + t2 * 16) * 16))[lane] = vo;
    }
    {
        const float ljs = ljacc + __shfl_xor(ljacc, 1);
        if ((lane & 1) == 0)
            out[(size_t)B_N * 16 + row0 + sp_t2 * 16 + sp_row] = ljs;
    }
}

extern "C" void kernel_launch(void* const* d_in, const int* in_sizes, int n_in,
                              void* d_out, int out_size, void* d_ws, size_t ws_size,
                              hipStream_t stream) {
    const float* x     = (const float*)d_in[0];
    const float* c     = (const float*)d_in[1];
    const float* W1s   = (const float*)d_in[2];
    const float* b1s   = (const float*)d_in[3];
    const float* Whs   = (const float*)d_in[4];
    const float* bhs   = (const float*)d_in[5];
    const float* Wos   = (const float*)d_in[6];
    const float* bos   = (const float*)d_in[7];
    const int*   perms = (const int*)d_in[8];
    float* out = (float*)d_out;
    _Float16* ws = (_Float16*)d_ws;

    prep_kernel<<<dim3(416), dim3(64), 0, stream>>>(W1s, b1s, Whs, Wos, ws);
    flow_mfma<<<dim3(B_N / 32), dim3(64), 0, stream>>>(
        x, c, bhs, bos, perms, ws, out);
}